// Round 6
// baseline (267.931 us; speedup 1.0000x reference)
//
#include <hip/hip_runtime.h>
#include <cstdint>
#include <cstddef>

typedef unsigned short u16;
typedef short bf16x8 __attribute__((ext_vector_type(8)));
typedef float floatx4 __attribute__((ext_vector_type(4)));

#define GLD16(gp, sp) __builtin_amdgcn_global_load_lds(                      \
    (const __attribute__((address_space(1))) void*)(gp),                     \
    (__attribute__((address_space(3))) void*)(sp), 16, 0, 0)

// counted vmem wait + full barrier (raw s_barrier, scheduling fence both sides)
#define VWAIT(N) asm volatile("s_waitcnt vmcnt(" #N ")" ::: "memory")
#define BARF()                                                               \
  do {                                                                       \
    __builtin_amdgcn_sched_barrier(0);                                       \
    __builtin_amdgcn_s_barrier();                                            \
    __builtin_amdgcn_sched_barrier(0);                                       \
  } while (0)

__device__ __forceinline__ u16 f2bf(float f) {
  unsigned u = __float_as_uint(f);
  u += 0x7fffu + ((u >> 16) & 1u);   // round-to-nearest-even
  return (u16)(u >> 16);
}

// ---------------- fused front: router (blocks 0..511) + weight transposes ----------------
// transpose: out[c][r] = bf16(in[r][c]), per-expert (R=1024 rows, C cols), 64x64 tiles.
__device__ __forceinline__ void transpose64(const float* __restrict__ inb, u16* __restrict__ outb,
                                            int C, int r0, int c0) {
  __shared__ float tileT[64][65];  // [col][row], +1 pad: writes/reads ~2-way (free)
  const int t = threadIdx.x;       // 256
  const int k = t & 15, w = t >> 4;
#pragma unroll
  for (int it = 0; it < 4; ++it) {
    const int r = r0 + w + it * 16;
    const float4 v = *(const float4*)(inb + (size_t)r * C + (c0 + k * 4));
    tileT[k * 4 + 0][w + it * 16] = v.x;
    tileT[k * 4 + 1][w + it * 16] = v.y;
    tileT[k * 4 + 2][w + it * 16] = v.z;
    tileT[k * 4 + 3][w + it * 16] = v.w;
  }
  __syncthreads();
#pragma unroll
  for (int it = 0; it < 4; ++it) {
    const int cc = w + it * 16;
    const int r4 = k * 4;
    ushort4 o;
    o.x = f2bf(tileT[cc][r4 + 0]);
    o.y = f2bf(tileT[cc][r4 + 1]);
    o.z = f2bf(tileT[cc][r4 + 2]);
    o.w = f2bf(tileT[cc][r4 + 3]);
    *(ushort4*)(outb + (size_t)(c0 + cc) * 1024 + r0 + r4) = o;
  }
}

__global__ __launch_bounds__(256) void front_kernel(
    const float* __restrict__ x, const float* __restrict__ rw, const float* __restrict__ rb,
    float* __restrict__ ew, int* __restrict__ eids, float* __restrict__ eprobs,
    const float* __restrict__ w1, u16* __restrict__ w1t,
    const float* __restrict__ w2, u16* __restrict__ w2t) {
  const int bid = blockIdx.x;
  if (bid >= 512) {
    int idx = bid - 512;
    if (idx < 4096) {  // w1: C=2048, 32 col-tiles x 16 row-tiles per expert
      const int e = idx >> 9, rem = idx & 511;
      const int ct = rem & 31, rt = rem >> 5;
      transpose64(w1 + (size_t)e * 1024 * 2048, w1t + (size_t)e * 2048 * 1024,
                  2048, rt * 64, ct * 64);
    } else {           // w2: C=1024, 16 x 16 per expert
      idx -= 4096;
      const int e = idx >> 8, rem = idx & 255;
      const int ct = rem & 15, rt = rem >> 4;
      transpose64(w2 + (size_t)e * 1024 * 1024, w2t + (size_t)e * 1024 * 1024,
                  1024, rt * 64, ct * 64);
    }
    return;
  }
  // ---- router ----
  const int wave = threadIdx.x >> 6, lane = threadIdx.x & 63;
  const int t = bid * 4 + wave;
  const float4* xv = (const float4*)(x + (size_t)t * 1024);
  float acc[8];
#pragma unroll
  for (int e = 0; e < 8; ++e) acc[e] = 0.f;
  for (int j = lane; j < 256; j += 64) {
    float4 xx = xv[j];
#pragma unroll
    for (int e = 0; e < 8; ++e) {
      float4 wv = ((const float4*)(rw + (size_t)e * 1024))[j];
      acc[e] += xx.x * wv.x + xx.y * wv.y + xx.z * wv.z + xx.w * wv.w;
    }
  }
#pragma unroll
  for (int e = 0; e < 8; ++e) {
    float v = acc[e];
#pragma unroll
    for (int off = 32; off > 0; off >>= 1) v += __shfl_down(v, off);
    acc[e] = v;
  }
  if (lane == 0) {
    float p[8];
    float mx = -1e30f;
#pragma unroll
    for (int e = 0; e < 8; ++e) { p[e] = acc[e] + rb[e]; mx = fmaxf(mx, p[e]); }
    float sum = 0.f;
#pragma unroll
    for (int e = 0; e < 8; ++e) { p[e] = __expf(p[e] - mx); sum += p[e]; }
    float inv = 1.f / sum;
#pragma unroll
    for (int e = 0; e < 8; ++e) p[e] *= inv;
    int i0 = 0;
#pragma unroll
    for (int e = 1; e < 8; ++e) if (p[e] > p[i0]) i0 = e;
    int i1 = (i0 == 0) ? 1 : 0;
#pragma unroll
    for (int e = 0; e < 8; ++e) if (e != i0 && e != i1 && p[e] > p[i1]) i1 = e;
    ew[t * 2 + 0] = p[i0];
    ew[t * 2 + 1] = p[i1];
    eids[t * 2 + 0] = i0;
    eids[t * 2 + 1] = i1;
    eprobs[t * 2 + 0] = p[i0];
    eprobs[t * 2 + 1] = p[i1];
  }
}

// ---------------- build per-expert token lists + work list (1 block) ----------------
// meta[0]=nWork, meta[1..40]=(e<<8)|rowBlock, meta[48+e]=slotBase[e]
__global__ void build_lists_kernel(const int* __restrict__ eids, const float* __restrict__ eprobs,
                                   int* __restrict__ row_token, float* __restrict__ row_scale,
                                   int* __restrict__ tok2slot, int* __restrict__ meta) {
  __shared__ int cnt[8], base[8], cur[8];
  const int tid = threadIdx.x;
  if (tid < 8) { cnt[tid] = 0; cur[tid] = 0; }
  __syncthreads();
  for (int t = tid; t < 2048; t += 256) {
    atomicAdd(&cnt[eids[t * 2 + 0]], 1);
    atomicAdd(&cnt[eids[t * 2 + 1]], 1);
  }
  __syncthreads();
  if (tid == 0) {
    int off = 0, w = 0;
    for (int e = 0; e < 8; ++e) {
      base[e] = off;
      meta[48 + e] = off;
      int nb = (cnt[e] + 127) >> 7;
      for (int rb = 0; rb < nb; ++rb) meta[1 + w++] = (e << 8) | rb;
      off += nb << 7;
    }
    meta[0] = w;  // <= 39
  }
  __syncthreads();
  for (int s = tid; s < 5120; s += 256) { row_token[s] = -1; row_scale[s] = 0.f; }
  __syncthreads();
  for (int t = tid; t < 2048; t += 256) {
#pragma unroll
    for (int k = 0; k < 2; ++k) {
      int e = eids[t * 2 + k];
      int s = base[e] + atomicAdd(&cur[e], 1);
      row_token[s] = t;
      row_scale[s] = eprobs[t * 2 + k];
      tok2slot[t * 2 + k] = s;
    }
  }
}

// ---------------- gather: xg[slot] = bf16(x[row_token[slot]]) (slot-ordered contiguous A) ----------------
__global__ void gather_x_kernel(const float* __restrict__ x, const int* __restrict__ row_token,
                                u16* __restrict__ xg) {
  const int s = blockIdx.x;             // 5120 slots
  int tk = row_token[s];
  if (tk < 0) tk = 0;                   // padded slot: copy token 0; masked by row_scale=0 later
  const float4* src = (const float4*)(x + (size_t)tk * 1024);
  ushort4* dst = (ushort4*)(xg + (size_t)s * 1024);
  const int t = threadIdx.x;            // 256 threads, 4 floats each
  float4 v = src[t];
  ushort4 o;
  o.x = f2bf(v.x); o.y = f2bf(v.y); o.z = f2bf(v.z); o.w = f2bf(v.w);
  dst[t] = o;
}

// ---------------- GEMM1 (contiguous slot rows) + bias + glu + scale -> actS ----------------
// 128x128 tile, 4 waves, 3-buffer depth-2 counted-vmcnt pipeline (R4 config, frozen).
__device__ __forceinline__ void g1_compute(const u16* AsR, const u16* BsR, int wr, int wc,
                                           int lane, floatx4 (&acc)[4][4]) {
  bf16x8 af[4], bfr[4];
#pragma unroll
  for (int mi = 0; mi < 4; ++mi) af[mi] = *(const bf16x8*)(AsR + (wr * 4 + mi) * 512 + lane * 8);
#pragma unroll
  for (int ni = 0; ni < 4; ++ni) bfr[ni] = *(const bf16x8*)(BsR + (wc * 4 + ni) * 512 + lane * 8);
  __builtin_amdgcn_s_setprio(1);
#pragma unroll
  for (int mi = 0; mi < 4; ++mi)
#pragma unroll
    for (int ni = 0; ni < 4; ++ni)
      acc[mi][ni] = __builtin_amdgcn_mfma_f32_16x16x32_bf16(af[mi], bfr[ni], acc[mi][ni], 0, 0, 0);
  __builtin_amdgcn_s_setprio(0);
}

__global__ __launch_bounds__(256) void gemm1_act_kernel(
    const u16* __restrict__ xg, const u16* __restrict__ w1t,
    const float* __restrict__ w1b, const float* __restrict__ row_scale,
    const int* __restrict__ meta, u16* __restrict__ actS) {
  if ((int)blockIdx.x >= meta[0]) return;
  __shared__ __align__(16) u16 As[3][128 * 32];
  __shared__ __align__(16) u16 Bs[3][128 * 32];
  const int w = meta[1 + blockIdx.x];
  const int e = w >> 8, rb = w & 255;
  const int slotB = meta[48 + e] + rb * 128;
  const int colBase = blockIdx.y * 128;
  const int tid = threadIdx.x, lane = tid & 63, wave = tid >> 6;
  const int row16 = lane & 15, chunk = lane >> 4;
  const u16* Bt = w1t + (size_t)e * 2048 * 1024;
  const u16* aP[2]; const u16* bP[2];
#pragma unroll
  for (int r = 0; r < 2; ++r) {
    int g = r * 4 + wave;
    aP[r] = xg + (size_t)(slotB + g * 16 + row16) * 1024 + chunk * 8;
    bP[r] = Bt + (size_t)(colBase + g * 16 + row16) * 1024 + chunk * 8;
  }
  const int wr = wave >> 1, wc = wave & 1;
  floatx4 acc[4][4];
#pragma unroll
  for (int mi = 0; mi < 4; ++mi)
#pragma unroll
    for (int ni = 0; ni < 4; ++ni) acc[mi][ni] = floatx4{0.f, 0.f, 0.f, 0.f};

#define G1_STAGE(W, KT)                                                      \
  {                                                                          \
    const int kk = (KT) * 32;                                                \
    GLD16(aP[0] + kk, As[W] + wave * 512);                                   \
    GLD16(bP[0] + kk, Bs[W] + wave * 512);                                   \
    GLD16(aP[1] + kk, As[W] + (4 + wave) * 512);                             \
    GLD16(bP[1] + kk, Bs[W] + (4 + wave) * 512);                             \
  }

  G1_STAGE(0, 0);
  G1_STAGE(1, 1);

#pragma unroll 1
  for (int kt = 0; kt < 30; kt += 3) {
    G1_STAGE(2, kt + 2); VWAIT(8); BARF();
    g1_compute(As[0], Bs[0], wr, wc, lane, acc); BARF();
    G1_STAGE(0, kt + 3); VWAIT(8); BARF();
    g1_compute(As[1], Bs[1], wr, wc, lane, acc); BARF();
    G1_STAGE(1, kt + 4); VWAIT(8); BARF();
    g1_compute(As[2], Bs[2], wr, wc, lane, acc); BARF();
  }
  VWAIT(4); BARF();
  g1_compute(As[0], Bs[0], wr, wc, lane, acc); BARF();
  VWAIT(0); BARF();
  g1_compute(As[1], Bs[1], wr, wc, lane, acc);
#undef G1_STAGE

  const int cl = lane & 15, ql = lane >> 4;
#pragma unroll
  for (int mi = 0; mi < 4; ++mi) {
#pragma unroll
    for (int r = 0; r < 4; ++r) {
      const int slot = slotB + wr * 64 + mi * 16 + ql * 4 + r;
      const float c = row_scale[slot];  // 0 for padded slots -> zero fill
#pragma unroll
      for (int ni = 0; ni < 4; ++ni) {
        const int n = colBase + wc * 64 + ni * 16 + cl;  // interleaved col of w1
        float v = acc[mi][ni][r] + w1b[e * 2048 + n];
        float o = __shfl_xor(v, 1);  // partner column
        if ((lane & 1) == 0) {       // even lane = gate col
          float g = fminf(v, 7.f);
          float u = fminf(fmaxf(o, -7.f), 7.f);
          float sg = 1.f / (1.f + __expf(-1.702f * g));
          float a = (u + 1.f) * (g * sg);
          actS[(size_t)slot * 1024 + (n >> 1)] = f2bf(c * a);
        }
      }
    }
  }
}

// ---------------- GEMM2: y[slot] = actS[slot] @ w2t[e]^T; BK=64, 16 MFMA/wave/phase ----------------
// A-tile 128x64 (16KB), B-tile 64x64 (8KB), 3 buffers (72KB LDS), 6 loads/wave/stage, vmcnt(12).
__device__ __forceinline__ void g2_compute(const u16* AsR, const u16* BsR, int wr, int wc,
                                           int lane, floatx4 (&acc)[4][2]) {
  bf16x8 af[2][4], bfr[2][2];
#pragma unroll
  for (int kk = 0; kk < 2; ++kk)
#pragma unroll
    for (int mi = 0; mi < 4; ++mi)
      af[kk][mi] = *(const bf16x8*)(AsR + (((wr * 4 + mi) * 2) + kk) * 512 + lane * 8);
#pragma unroll
  for (int kk = 0; kk < 2; ++kk)
#pragma unroll
    for (int ni = 0; ni < 2; ++ni)
      bfr[kk][ni] = *(const bf16x8*)(BsR + (((wc * 2 + ni) * 2) + kk) * 512 + lane * 8);
  __builtin_amdgcn_s_setprio(1);
#pragma unroll
  for (int kk = 0; kk < 2; ++kk)
#pragma unroll
    for (int mi = 0; mi < 4; ++mi)
#pragma unroll
      for (int ni = 0; ni < 2; ++ni)
        acc[mi][ni] = __builtin_amdgcn_mfma_f32_16x16x32_bf16(af[kk][mi], bfr[kk][ni], acc[mi][ni], 0, 0, 0);
  __builtin_amdgcn_s_setprio(0);
}

__global__ __launch_bounds__(256) void gemm2_kernel(
    const u16* __restrict__ actS, const u16* __restrict__ w2t,
    const int* __restrict__ meta, float* __restrict__ y) {
  if ((int)blockIdx.x >= meta[0]) return;
  __shared__ __align__(16) u16 As[3][128 * 64];  // 16KB each
  __shared__ __align__(16) u16 Bs[3][64 * 64];   // 8KB each
  const int w = meta[1 + blockIdx.x];
  const int e = w >> 8, rb = w & 255;
  const int slotB = meta[48 + e] + rb * 128;
  const int colBase = blockIdx.y * 64;
  const int tid = threadIdx.x, lane = tid & 63, wave = tid >> 6;
  const int row16 = lane & 15, chunk = lane >> 4;
  const u16* Bt = w2t + (size_t)e * 1024 * 1024;
  const u16* aP[2]; const u16* bP;
#pragma unroll
  for (int r = 0; r < 2; ++r) {
    int g = r * 4 + wave;
    aP[r] = actS + (size_t)(slotB + g * 16 + row16) * 1024 + chunk * 8;
  }
  bP = Bt + (size_t)(colBase + wave * 16 + row16) * 1024 + chunk * 8;
  const int wr = wave >> 1, wc = wave & 1;
  floatx4 acc[4][2];
#pragma unroll
  for (int mi = 0; mi < 4; ++mi)
#pragma unroll
    for (int ni = 0; ni < 2; ++ni) acc[mi][ni] = floatx4{0.f, 0.f, 0.f, 0.f};

  // per-wave LDS group bases: A groups wave and 4+wave (2KB each), B group wave
#define G2_STAGE(W, KT)                                                      \
  {                                                                          \
    const int kb = (KT) * 64;                                                \
    GLD16(aP[0] + kb,      As[W] + (wave * 2 + 0) * 512);                    \
    GLD16(aP[0] + kb + 32, As[W] + (wave * 2 + 1) * 512);                    \
    GLD16(aP[1] + kb,      As[W] + ((4 + wave) * 2 + 0) * 512);              \
    GLD16(aP[1] + kb + 32, As[W] + ((4 + wave) * 2 + 1) * 512);              \
    GLD16(bP + kb,         Bs[W] + (wave * 2 + 0) * 512);                    \
    GLD16(bP + kb + 32,    Bs[W] + (wave * 2 + 1) * 512);                    \
  }

  // 16 K-tiles of 64. Prologue: tiles 0,1 (12 loads in flight).
  G2_STAGE(0, 0);
  G2_STAGE(1, 1);

#pragma unroll 1
  for (int kt = 0; kt < 12; kt += 3) {
    G2_STAGE(2, kt + 2); VWAIT(12); BARF();
    g2_compute(As[0], Bs[0], wr, wc, lane, acc); BARF();
    G2_STAGE(0, kt + 3); VWAIT(12); BARF();
    g2_compute(As[1], Bs[1], wr, wc, lane, acc); BARF();
    G2_STAGE(1, kt + 4); VWAIT(12); BARF();
    g2_compute(As[2], Bs[2], wr, wc, lane, acc); BARF();
  }
  // computed 0..11; staged up to 13. Remaining tiles 12..15.
  G2_STAGE(2, 14); VWAIT(12); BARF();
  g2_compute(As[0], Bs[0], wr, wc, lane, acc); BARF();   // tile 12
  G2_STAGE(0, 15); VWAIT(12); BARF();
  g2_compute(As[1], Bs[1], wr, wc, lane, acc); BARF();   // tile 13
  VWAIT(6); BARF();
  g2_compute(As[2], Bs[2], wr, wc, lane, acc); BARF();   // tile 14
  VWAIT(0); BARF();
  g2_compute(As[0], Bs[0], wr, wc, lane, acc);           // tile 15
#undef G2_STAGE

  const int cl = lane & 15, ql = lane >> 4;
#pragma unroll
  for (int mi = 0; mi < 4; ++mi)
#pragma unroll
    for (int r = 0; r < 4; ++r) {
      const int slot = slotB + wr * 64 + mi * 16 + ql * 4 + r;
#pragma unroll
      for (int ni = 0; ni < 2; ++ni) {
        const int col = colBase + wc * 32 + ni * 16 + cl;
        y[(size_t)slot * 1024 + col] = acc[mi][ni][r];
      }
    }
}

// ---------------- combine: out[t,h] = p0*w2b[e0,h] + p1*w2b[e1,h] + y[s0,h] + y[s1,h] ----------------
__global__ void combine_kernel(const float* __restrict__ y, const int* __restrict__ eids,
                               const float* __restrict__ eprobs, const int* __restrict__ tok2slot,
                               const float* __restrict__ w2b, float* __restrict__ out) {
  int idx = blockIdx.x * 256 + threadIdx.x;  // < 2048*1024
  int t = idx >> 10, h = idx & 1023;
  int e0 = eids[t * 2], e1 = eids[t * 2 + 1];
  int s0 = tok2slot[t * 2], s1 = tok2slot[t * 2 + 1];
  out[idx] = eprobs[t * 2] * w2b[e0 * 1024 + h] + eprobs[t * 2 + 1] * w2b[e1 * 1024 + h]
           + y[(size_t)s0 * 1024 + h] + y[(size_t)s1 * 1024 + h];
}

extern "C" void kernel_launch(void* const* d_in, const int* in_sizes, int n_in,
                              void* d_out, int out_size, void* d_ws, size_t ws_size,
                              hipStream_t stream) {
  const float* x   = (const float*)d_in[0];   // (2048, 1024)
  const float* rw  = (const float*)d_in[1];   // (8, 1024)
  const float* rb  = (const float*)d_in[2];   // (8,)
  const float* w1  = (const float*)d_in[3];   // (8, 1024, 2048)
  const float* w1b = (const float*)d_in[4];   // (8, 2048)
  const float* w2  = (const float*)d_in[5];   // (8, 1024, 1024)
  const float* w2b = (const float*)d_in[6];   // (8, 1024)
  float* out = (float*)d_out;                 // 2048*1024
  float* ew  = out + (size_t)2048 * 1024;     // 2048*2

  char* ws = (char*)d_ws;
  u16* xg        = (u16*)(ws);                                   // 10 MiB  (5120, 1024) gathered bf16 rows
  u16* w1t       = (u16*)(ws + (10ull << 20));                   // 32 MiB  (E, 2I, H)
  float* y       = (float*)(ws + (10ull << 20));                 // 20 MiB, reuses w1t (dead after gemm1)
  u16* w2t       = (u16*)(ws + (42ull << 20));                   // 16 MiB  (E, H, I)
  u16* actS      = (u16*)(ws + (58ull << 20));                   // 10 MiB  (5120, 1024)
  int* eids      = (int*)(ws + (68ull << 20));                   // 16 KiB
  float* eprobs  = (float*)(ws + (68ull << 20) + (16 << 10));    // 16 KiB
  int* row_token = (int*)(ws + (68ull << 20) + (32 << 10));      // 20 KiB
  float* row_scale = (float*)(ws + (68ull << 20) + (52 << 10));  // 20 KiB
  int* meta      = (int*)(ws + (68ull << 20) + (72 << 10));      // 1 KiB
  int* tok2slot  = (int*)(ws + (68ull << 20) + (74 << 10));      // 16 KiB

  front_kernel<<<512 + 4096 + 2048, 256, 0, stream>>>(x, rw, rb, ew, eids, eprobs,
                                                      w1, w1t, w2, w2t);
  build_lists_kernel<<<1, 256, 0, stream>>>(eids, eprobs, row_token, row_scale, tok2slot, meta);
  gather_x_kernel<<<5120, 256, 0, stream>>>(x, row_token, xg);
  gemm1_act_kernel<<<dim3(40, 16), 256, 0, stream>>>(xg, w1t, w1b, row_scale, meta, actS);
  gemm2_kernel<<<dim3(40, 16), 256, 0, stream>>>(actS, w2t, meta, y);
  combine_kernel<<<8192, 256, 0, stream>>>(y, eids, eprobs, tok2slot, w2b, out);
}

// Round 9
// 250.520 us; speedup vs baseline: 1.0695x; 1.0695x over previous
//
#include <hip/hip_runtime.h>
#include <cstdint>
#include <cstddef>

typedef unsigned short u16;
typedef short bf16x8 __attribute__((ext_vector_type(8)));
typedef float floatx4 __attribute__((ext_vector_type(4)));

#define GLD16(gp, sp) __builtin_amdgcn_global_load_lds(                      \
    (const __attribute__((address_space(1))) void*)(gp),                     \
    (__attribute__((address_space(3))) void*)(sp), 16, 0, 0)

#define VWAIT(N) asm volatile("s_waitcnt vmcnt(" #N ")" ::: "memory")
#define BARF()                                                               \
  do {                                                                       \
    __builtin_amdgcn_sched_barrier(0);                                       \
    __builtin_amdgcn_s_barrier();                                            \
    __builtin_amdgcn_sched_barrier(0);                                       \
  } while (0)

__device__ __forceinline__ u16 f2bf(float f) {
  unsigned u = __float_as_uint(f);
  u += 0x7fffu + ((u >> 16) & 1u);   // round-to-nearest-even
  return (u16)(u >> 16);
}

// ---------------- fused front: router+xb (blocks 0..511) + weight transposes ----------------
__device__ __forceinline__ void transpose64(const float* __restrict__ inb, u16* __restrict__ outb,
                                            int C, int r0, int c0) {
  __shared__ float tileT[64][65];
  const int t = threadIdx.x;       // 256
  const int k = t & 15, w = t >> 4;
#pragma unroll
  for (int it = 0; it < 4; ++it) {
    const int r = r0 + w + it * 16;
    const float4 v = *(const float4*)(inb + (size_t)r * C + (c0 + k * 4));
    tileT[k * 4 + 0][w + it * 16] = v.x;
    tileT[k * 4 + 1][w + it * 16] = v.y;
    tileT[k * 4 + 2][w + it * 16] = v.z;
    tileT[k * 4 + 3][w + it * 16] = v.w;
  }
  __syncthreads();
#pragma unroll
  for (int it = 0; it < 4; ++it) {
    const int cc = w + it * 16;
    const int r4 = k * 4;
    ushort4 o;
    o.x = f2bf(tileT[cc][r4 + 0]);
    o.y = f2bf(tileT[cc][r4 + 1]);
    o.z = f2bf(tileT[cc][r4 + 2]);
    o.w = f2bf(tileT[cc][r4 + 3]);
    *(ushort4*)(outb + (size_t)(c0 + cc) * 1024 + r0 + r4) = o;
  }
}

__global__ __launch_bounds__(256) void front_kernel(
    const float* __restrict__ x, const float* __restrict__ rw, const float* __restrict__ rb,
    float* __restrict__ ew, int* __restrict__ eids, float* __restrict__ eprobs,
    u16* __restrict__ xb,
    const float* __restrict__ w1, u16* __restrict__ w1t,
    const float* __restrict__ w2, u16* __restrict__ w2t) {
  const int bid = blockIdx.x;
  if (bid >= 512) {
    int idx = bid - 512;
    if (idx < 4096) {  // w1: C=2048, 32 col-tiles x 16 row-tiles per expert
      const int e = idx >> 9, rem = idx & 511;
      const int ct = rem & 31, rt = rem >> 5;
      transpose64(w1 + (size_t)e * 1024 * 2048, w1t + (size_t)e * 2048 * 1024,
                  2048, rt * 64, ct * 64);
    } else {           // w2: C=1024, 16 x 16 per expert
      idx -= 4096;
      const int e = idx >> 8, rem = idx & 255;
      const int ct = rem & 15, rt = rem >> 4;
      transpose64(w2 + (size_t)e * 1024 * 1024, w2t + (size_t)e * 1024 * 1024,
                  1024, rt * 64, ct * 64);
    }
    return;
  }
  // ---- router + xb cvt (R2-proven body) ----
  const int wave = threadIdx.x >> 6, lane = threadIdx.x & 63;
  const int t = bid * 4 + wave;
  const float4* xv = (const float4*)(x + (size_t)t * 1024);
  ushort4* xo = (ushort4*)(xb + (size_t)t * 1024);
  float acc[8];
#pragma unroll
  for (int e = 0; e < 8; ++e) acc[e] = 0.f;
  for (int j = lane; j < 256; j += 64) {
    float4 xx = xv[j];
    ushort4 o;
    o.x = f2bf(xx.x); o.y = f2bf(xx.y); o.z = f2bf(xx.z); o.w = f2bf(xx.w);
    xo[j] = o;
#pragma unroll
    for (int e = 0; e < 8; ++e) {
      float4 wv = ((const float4*)(rw + (size_t)e * 1024))[j];
      acc[e] += xx.x * wv.x + xx.y * wv.y + xx.z * wv.z + xx.w * wv.w;
    }
  }
#pragma unroll
  for (int e = 0; e < 8; ++e) {
    float v = acc[e];
#pragma unroll
    for (int off = 32; off > 0; off >>= 1) v += __shfl_down(v, off);
    acc[e] = v;
  }
  if (lane == 0) {
    float p[8];
    float mx = -1e30f;
#pragma unroll
    for (int e = 0; e < 8; ++e) { p[e] = acc[e] + rb[e]; mx = fmaxf(mx, p[e]); }
    float sum = 0.f;
#pragma unroll
    for (int e = 0; e < 8; ++e) { p[e] = __expf(p[e] - mx); sum += p[e]; }
    float inv = 1.f / sum;
#pragma unroll
    for (int e = 0; e < 8; ++e) p[e] *= inv;
    int i0 = 0;
#pragma unroll
    for (int e = 1; e < 8; ++e) if (p[e] > p[i0]) i0 = e;
    int i1 = (i0 == 0) ? 1 : 0;
#pragma unroll
    for (int e = 0; e < 8; ++e) if (e != i0 && e != i1 && p[e] > p[i1]) i1 = e;
    ew[t * 2 + 0] = p[i0];
    ew[t * 2 + 1] = p[i1];
    eids[t * 2 + 0] = i0;
    eids[t * 2 + 1] = i1;
    eprobs[t * 2 + 0] = p[i0];
    eprobs[t * 2 + 1] = p[i1];
  }
}

// ---------------- build per-expert token lists + work list (1 block, R2-proven) ----------------
__global__ void build_lists_kernel(const int* __restrict__ eids, const float* __restrict__ eprobs,
                                   int* __restrict__ row_token, float* __restrict__ row_scale,
                                   int* __restrict__ tok2slot, int* __restrict__ meta) {
  __shared__ int cnt[8], base[8], cur[8];
  const int tid = threadIdx.x;
  if (tid < 8) { cnt[tid] = 0; cur[tid] = 0; }
  __syncthreads();
  for (int t = tid; t < 2048; t += 256) {
    atomicAdd(&cnt[eids[t * 2 + 0]], 1);
    atomicAdd(&cnt[eids[t * 2 + 1]], 1);
  }
  __syncthreads();
  if (tid == 0) {
    int off = 0, w = 0;
    for (int e = 0; e < 8; ++e) {
      base[e] = off;
      meta[48 + e] = off;
      int nb = (cnt[e] + 127) >> 7;
      for (int rb = 0; rb < nb; ++rb) meta[1 + w++] = (e << 8) | rb;
      off += nb << 7;
    }
    meta[0] = w;  // <= 39
  }
  __syncthreads();
  for (int s = tid; s < 5120; s += 256) { row_token[s] = -1; row_scale[s] = 0.f; }
  __syncthreads();
  for (int t = tid; t < 2048; t += 256) {
#pragma unroll
    for (int k = 0; k < 2; ++k) {
      int e = eids[t * 2 + k];
      int s = base[e] + atomicAdd(&cur[e], 1);
      row_token[s] = t;
      row_scale[s] = eprobs[t * 2 + k];
      tok2slot[t * 2 + k] = s;
    }
  }
}

// ---------------- GEMM1 (R2-proven, verbatim): 128x128, 3-buf counted-vmcnt ----------------
__device__ __forceinline__ void g1_compute(const u16* AsR, const u16* BsR, int wr, int wc,
                                           int lane, floatx4 (&acc)[4][4]) {
  bf16x8 af[4], bfr[4];
#pragma unroll
  for (int mi = 0; mi < 4; ++mi) af[mi] = *(const bf16x8*)(AsR + (wr * 4 + mi) * 512 + lane * 8);
#pragma unroll
  for (int ni = 0; ni < 4; ++ni) bfr[ni] = *(const bf16x8*)(BsR + (wc * 4 + ni) * 512 + lane * 8);
  __builtin_amdgcn_s_setprio(1);
#pragma unroll
  for (int mi = 0; mi < 4; ++mi)
#pragma unroll
    for (int ni = 0; ni < 4; ++ni)
      acc[mi][ni] = __builtin_amdgcn_mfma_f32_16x16x32_bf16(af[mi], bfr[ni], acc[mi][ni], 0, 0, 0);
  __builtin_amdgcn_s_setprio(0);
}

__global__ __launch_bounds__(256) void gemm1_act_kernel(
    const u16* __restrict__ xb, const u16* __restrict__ w1t,
    const float* __restrict__ w1b,
    const int* __restrict__ row_token, const float* __restrict__ row_scale,
    const int* __restrict__ meta, u16* __restrict__ actS) {
  if ((int)blockIdx.x >= meta[0]) return;
  __shared__ __align__(16) u16 As[3][128 * 32];
  __shared__ __align__(16) u16 Bs[3][128 * 32];
  const int w = meta[1 + blockIdx.x];
  const int e = w >> 8, rb = w & 255;
  const int slotB = meta[48 + e] + rb * 128;
  const int colBase = blockIdx.y * 128;
  const int tid = threadIdx.x, lane = tid & 63, wave = tid >> 6;
  const int row16 = lane & 15, chunk = lane >> 4;
  const u16* Bt = w1t + (size_t)e * 2048 * 1024;
  const u16* aP[2]; const u16* bP[2];
#pragma unroll
  for (int r = 0; r < 2; ++r) {
    int g = r * 4 + wave;
    int tk = row_token[slotB + g * 16 + row16];
    if (tk < 0) tk = 0;
    aP[r] = xb + (size_t)tk * 1024 + chunk * 8;
    bP[r] = Bt + (size_t)(colBase + g * 16 + row16) * 1024 + chunk * 8;
  }
  const int wr = wave >> 1, wc = wave & 1;
  floatx4 acc[4][4];
#pragma unroll
  for (int mi = 0; mi < 4; ++mi)
#pragma unroll
    for (int ni = 0; ni < 4; ++ni) acc[mi][ni] = floatx4{0.f, 0.f, 0.f, 0.f};

#define G1_STAGE(W, KT)                                                      \
  {                                                                          \
    const int kk = (KT) * 32;                                                \
    GLD16(aP[0] + kk, As[W] + wave * 512);                                   \
    GLD16(bP[0] + kk, Bs[W] + wave * 512);                                   \
    GLD16(aP[1] + kk, As[W] + (4 + wave) * 512);                             \
    GLD16(bP[1] + kk, Bs[W] + (4 + wave) * 512);                             \
  }

  G1_STAGE(0, 0);
  G1_STAGE(1, 1);

#pragma unroll 1
  for (int kt = 0; kt < 30; kt += 3) {
    G1_STAGE(2, kt + 2); VWAIT(8); BARF();
    g1_compute(As[0], Bs[0], wr, wc, lane, acc); BARF();
    G1_STAGE(0, kt + 3); VWAIT(8); BARF();
    g1_compute(As[1], Bs[1], wr, wc, lane, acc); BARF();
    G1_STAGE(1, kt + 4); VWAIT(8); BARF();
    g1_compute(As[2], Bs[2], wr, wc, lane, acc); BARF();
  }
  VWAIT(4); BARF();
  g1_compute(As[0], Bs[0], wr, wc, lane, acc); BARF();
  VWAIT(0); BARF();
  g1_compute(As[1], Bs[1], wr, wc, lane, acc);
#undef G1_STAGE

  const int cl = lane & 15, ql = lane >> 4;
#pragma unroll
  for (int mi = 0; mi < 4; ++mi) {
#pragma unroll
    for (int r = 0; r < 4; ++r) {
      const int slot = slotB + wr * 64 + mi * 16 + ql * 4 + r;
      const float c = row_scale[slot];  // 0 for padded slots -> zero fill
#pragma unroll
      for (int ni = 0; ni < 4; ++ni) {
        const int n = colBase + wc * 64 + ni * 16 + cl;  // interleaved col of w1
        float v = acc[mi][ni][r] + w1b[e * 2048 + n];
        float o = __shfl_xor(v, 1);  // partner column
        if ((lane & 1) == 0) {       // even lane = gate col
          float g = fminf(v, 7.f);
          float u = fminf(fmaxf(o, -7.f), 7.f);
          float sg = 1.f / (1.f + __expf(-1.702f * g));
          float a = (u + 1.f) * (g * sg);
          actS[(size_t)slot * 1024 + (n >> 1)] = f2bf(c * a);
        }
      }
    }
  }
}

// ---------------- GEMM2: identical structure to gemm1 (128x128, 16 MFMA/wave/phase) ----------------
__global__ __launch_bounds__(256) void gemm2_kernel(
    const u16* __restrict__ actS, const u16* __restrict__ w2t,
    const int* __restrict__ meta, float* __restrict__ y) {
  if ((int)blockIdx.x >= meta[0]) return;
  __shared__ __align__(16) u16 As[3][128 * 32];
  __shared__ __align__(16) u16 Bs[3][128 * 32];
  const int w = meta[1 + blockIdx.x];
  const int e = w >> 8, rb = w & 255;
  const int slotB = meta[48 + e] + rb * 128;
  const int colBase = blockIdx.y * 128;
  const int tid = threadIdx.x, lane = tid & 63, wave = tid >> 6;
  const int row16 = lane & 15, chunk = lane >> 4;
  const u16* Bt = w2t + (size_t)e * 1024 * 1024;
  const u16* aP[2]; const u16* bP[2];
#pragma unroll
  for (int r = 0; r < 2; ++r) {
    int g = r * 4 + wave;
    aP[r] = actS + (size_t)(slotB + g * 16 + row16) * 1024 + chunk * 8;
    bP[r] = Bt + (size_t)(colBase + g * 16 + row16) * 1024 + chunk * 8;
  }
  const int wr = wave >> 1, wc = wave & 1;
  floatx4 acc[4][4];
#pragma unroll
  for (int mi = 0; mi < 4; ++mi)
#pragma unroll
    for (int ni = 0; ni < 4; ++ni) acc[mi][ni] = floatx4{0.f, 0.f, 0.f, 0.f};

#define G2_STAGE(W, KT)                                                      \
  {                                                                          \
    const int kk = (KT) * 32;                                                \
    GLD16(aP[0] + kk, As[W] + wave * 512);                                   \
    GLD16(bP[0] + kk, Bs[W] + wave * 512);                                   \
    GLD16(aP[1] + kk, As[W] + (4 + wave) * 512);                             \
    GLD16(bP[1] + kk, Bs[W] + (4 + wave) * 512);                             \
  }

  G2_STAGE(0, 0);
  G2_STAGE(1, 1);

#pragma unroll 1
  for (int kt = 0; kt < 30; kt += 3) {
    G2_STAGE(2, kt + 2); VWAIT(8); BARF();
    g1_compute(As[0], Bs[0], wr, wc, lane, acc); BARF();
    G2_STAGE(0, kt + 3); VWAIT(8); BARF();
    g1_compute(As[1], Bs[1], wr, wc, lane, acc); BARF();
    G2_STAGE(1, kt + 4); VWAIT(8); BARF();
    g1_compute(As[2], Bs[2], wr, wc, lane, acc); BARF();
  }
  VWAIT(4); BARF();
  g1_compute(As[0], Bs[0], wr, wc, lane, acc); BARF();
  VWAIT(0); BARF();
  g1_compute(As[1], Bs[1], wr, wc, lane, acc);
#undef G2_STAGE

  const int cl = lane & 15, ql = lane >> 4;
#pragma unroll
  for (int mi = 0; mi < 4; ++mi)
#pragma unroll
    for (int r = 0; r < 4; ++r) {
      const int slot = slotB + wr * 64 + mi * 16 + ql * 4 + r;
#pragma unroll
      for (int ni = 0; ni < 4; ++ni) {
        const int col = colBase + wc * 64 + ni * 16 + cl;
        y[(size_t)slot * 1024 + col] = acc[mi][ni][r];
      }
    }
}

// ---------------- combine (R2-proven) ----------------
__global__ void combine_kernel(const float* __restrict__ y, const int* __restrict__ eids,
                               const float* __restrict__ eprobs, const int* __restrict__ tok2slot,
                               const float* __restrict__ w2b, float* __restrict__ out) {
  int idx = blockIdx.x * 256 + threadIdx.x;  // < 2048*1024
  int t = idx >> 10, h = idx & 1023;
  int e0 = eids[t * 2], e1 = eids[t * 2 + 1];
  int s0 = tok2slot[t * 2], s1 = tok2slot[t * 2 + 1];
  out[idx] = eprobs[t * 2] * w2b[e0 * 1024 + h] + eprobs[t * 2 + 1] * w2b[e1 * 1024 + h]
           + y[(size_t)s0 * 1024 + h] + y[(size_t)s1 * 1024 + h];
}

extern "C" void kernel_launch(void* const* d_in, const int* in_sizes, int n_in,
                              void* d_out, int out_size, void* d_ws, size_t ws_size,
                              hipStream_t stream) {
  const float* x   = (const float*)d_in[0];   // (2048, 1024)
  const float* rw  = (const float*)d_in[1];   // (8, 1024)
  const float* rb  = (const float*)d_in[2];   // (8,)
  const float* w1  = (const float*)d_in[3];   // (8, 1024, 2048)
  const float* w1b = (const float*)d_in[4];   // (8, 2048)
  const float* w2  = (const float*)d_in[5];   // (8, 1024, 1024)
  const float* w2b = (const float*)d_in[6];   // (8, 1024)
  float* out = (float*)d_out;                 // 2048*1024
  float* ew  = out + (size_t)2048 * 1024;     // 2048*2

  char* ws = (char*)d_ws;
  u16* xb        = (u16*)(ws);                                   //  4 MiB
  u16* w1t       = (u16*)(ws + (4ull << 20));                    // 32 MiB  (E, 2I, H)
  float* y       = (float*)(ws + (4ull << 20));                  // 20 MiB, reuses w1t (dead after gemm1)
  u16* w2t       = (u16*)(ws + (36ull << 20));                   // 16 MiB  (E, H, I)
  u16* actS      = (u16*)(ws + (52ull << 20));                   // 10 MiB  (5120, 1024)
  int* eids      = (int*)(ws + (62ull << 20));                   // 16 KiB
  float* eprobs  = (float*)(ws + (62ull << 20) + (16 << 10));    // 16 KiB
  int* row_token = (int*)(ws + (62ull << 20) + (32 << 10));      // 20 KiB
  float* row_scale = (float*)(ws + (62ull << 20) + (52 << 10));  // 20 KiB
  int* meta      = (int*)(ws + (62ull << 20) + (72 << 10));      // 1 KiB
  int* tok2slot  = (int*)(ws + (62ull << 20) + (74 << 10));      // 16 KiB

  front_kernel<<<512 + 4096 + 2048, 256, 0, stream>>>(x, rw, rb, ew, eids, eprobs, xb,
                                                      w1, w1t, w2, w2t);
  build_lists_kernel<<<1, 256, 0, stream>>>(eids, eprobs, row_token, row_scale, tok2slot, meta);
  gemm1_act_kernel<<<dim3(40, 16), 256, 0, stream>>>(xb, w1t, w1b, row_token, row_scale, meta, actS);
  gemm2_kernel<<<dim3(40, 8), 256, 0, stream>>>(actS, w2t, meta, y);
  combine_kernel<<<8192, 256, 0, stream>>>(y, eids, eprobs, tok2slot, w2b, out);
}